// Round 11
// baseline (200.647 us; speedup 1.0000x reference)
//
#include <hip/hip_runtime.h>
#include <hip/hip_bf16.h>

#define I_DIM  512
#define O_DIM  512
#define NBATCH 1024
#define NSPL   8            // spline coeffs per input channel
#define KPI    12           // K slots per input channel: 8 spline + s_hi,s_hi,s_lo,0
#define KDIM   (I_DIM * KPI)   // 6144
#define NGRID  12           // extended grid points per channel

#define SPLITK 4
#define KSEG   (KDIM / SPLITK) // 1536
#define BK     128             // bf16 elems per LDS row; 256 B
#define BM     64
#define BN     64
#define NT     (KSEG / BK)     // 12 K-iterations (even)

typedef __attribute__((ext_vector_type(8))) short bf16x8;
typedef __attribute__((ext_vector_type(4))) float f32x4;

// ---------------------------------------------------------------------------
// async global->LDS 16B: dest = wave-uniform base + lane*16 (m97/m104 semantics)
// ---------------------------------------------------------------------------
__device__ __forceinline__ void gload_lds16(const __hip_bfloat16* g, __hip_bfloat16* l) {
    __builtin_amdgcn_global_load_lds(
        (const __attribute__((address_space(1))) void*)g,
        (__attribute__((address_space(3))) void*)l, 16, 0, 0);
}

// ---------------------------------------------------------------------------
// Device-coherent (agent-scope) store/load: emit global_store/load with sc1 ->
// write-through / read at L3 (the cross-XCD coherence point). NO L2 writeback
// involved -- this is the fence-free alternative to R7's __threadfence poison.
// ---------------------------------------------------------------------------
__device__ __forceinline__ void st_dev(float* p, float v) {
    __hip_atomic_store(p, v, __ATOMIC_RELAXED, __HIP_MEMORY_SCOPE_AGENT);
}
__device__ __forceinline__ float ld_dev(const float* p) {
    return __hip_atomic_load(p, __ATOMIC_RELAXED, __HIP_MEMORY_SCOPE_AGENT);
}

// ---------------------------------------------------------------------------
// Feature row: F[b][i*12+slot] = [B0..B7, s_hi, s_hi, s_lo, 0] (bf16).
// R8: grid is broadcast linspace -> shared knot row, uniform spacing ->
// 3 reciprocals replace 54 divides (-21us measured).
// ---------------------------------------------------------------------------
__device__ __forceinline__ void features_core(float xv, const float* __restrict__ grid,
                                              __hip_bfloat16* __restrict__ dst) {
    float g[NGRID];
#pragma unroll
    for (int j = 0; j < NGRID; ++j) g[j] = grid[j];   // uniform across lanes

    float h  = g[1] - g[0];
    float r1 = 1.0f / h;
    float r2 = 1.0f / (2.0f * h);
    float r3 = 1.0f / (3.0f * h);

    float B[NGRID - 1];
#pragma unroll
    for (int j = 0; j < NGRID - 1; ++j)
        B[j] = (xv >= g[j] && xv < g[j + 1]) ? 1.0f : 0.0f;

#pragma unroll
    for (int j = 0; j < NGRID - 2; ++j)
        B[j] = (xv - g[j]) * r1 * B[j] + (g[j + 2] - xv) * r1 * B[j + 1];
#pragma unroll
    for (int j = 0; j < NGRID - 3; ++j)
        B[j] = (xv - g[j]) * r2 * B[j] + (g[j + 3] - xv) * r2 * B[j + 1];
#pragma unroll
    for (int j = 0; j < NGRID - 4; ++j)
        B[j] = (xv - g[j]) * r3 * B[j] + (g[j + 4] - xv) * r3 * B[j + 1];

    float s = xv / (1.0f + __expf(-xv));  // silu
    __hip_bfloat16 shi = __float2bfloat16(s);
    __hip_bfloat16 slo = __float2bfloat16(s - __bfloat162float(shi));

    __align__(16) __hip_bfloat16 row[KPI];
#pragma unroll
    for (int k = 0; k < NSPL; ++k) row[k] = __float2bfloat16(B[k]);
    row[8]  = shi;
    row[9]  = shi;
    row[10] = slo;
    row[11] = __float2bfloat16(0.0f);

    uint2* d = (uint2*)dst;
    const uint2* srow = (const uint2*)row;
    d[0] = srow[0]; d[1] = srow[1]; d[2] = srow[2];
}

__device__ __forceinline__ void wt_row_core(const float* __restrict__ coef,
                                            const float* __restrict__ sb,
                                            const float* __restrict__ sp,
                                            int i, int o,
                                            __hip_bfloat16* __restrict__ W) {
    float sbv = sb[i * O_DIM + o];
    float spv = sp[i * O_DIM + o];
    const float* cf = coef + (size_t)(i * O_DIM + o) * NSPL;
    __align__(16) __hip_bfloat16 row[KPI];
#pragma unroll
    for (int k = 0; k < NSPL; ++k) row[k] = __float2bfloat16(spv * cf[k]);
    __hip_bfloat16 whi = __float2bfloat16(sbv);
    __hip_bfloat16 wlo = __float2bfloat16(sbv - __bfloat162float(whi));
    row[8]  = whi;
    row[9]  = wlo;
    row[10] = whi;
    row[11] = __float2bfloat16(0.0f);
    uint2* dst = (uint2*)(W + (size_t)o * KDIM + i * KPI);
    const uint2* src = (const uint2*)row;
    dst[0] = src[0]; dst[1] = src[1]; dst[2] = src[2];
}

// ---------------------------------------------------------------------------
// prep: one launch for Wt-build (all 3 layers) + layer-0 features + ticket
// counter zeroing (3x128 ints, blocks 0-1).
// ---------------------------------------------------------------------------
#define WT_BLOCKS   3072   // 3 layers x (8 i-tiles x 128 o-tiles)
#define FEAT_BLOCKS 2048   // NBATCH*I_DIM / 256
#define NCTR        (3 * 128)
__global__ __launch_bounds__(256)
void prep_kernel(const float* __restrict__ x0, const float* __restrict__ gr0,
                 const float* __restrict__ c0, const float* __restrict__ sb0, const float* __restrict__ sp0,
                 const float* __restrict__ c1, const float* __restrict__ sb1, const float* __restrict__ sp1,
                 const float* __restrict__ c2, const float* __restrict__ sb2, const float* __restrict__ sp2,
                 __hip_bfloat16* __restrict__ Wt,   // [3][O_DIM][KDIM]
                 __hip_bfloat16* __restrict__ F0,   // [NBATCH][KDIM]
                 int* __restrict__ ctr) {           // [3][128] splitK tickets
    int b = blockIdx.x;
    int t = threadIdx.x;
    int z = b * 256 + t;
    if (z < NCTR) ctr[z] = 0;
    if (b < WT_BLOCKS) {
        int l   = b >> 10;            // 0..2
        int rem = b & 1023;
        int i0  = (rem & 7) * 64;     // 8 i-tiles
        int o0  = (rem >> 3) * 4;     // 128 o-tiles
        const float* coef = l == 0 ? c0  : (l == 1 ? c1  : c2);
        const float* sb   = l == 0 ? sb0 : (l == 1 ? sb1 : sb2);
        const float* sp   = l == 0 ? sp0 : (l == 1 ? sp1 : sp2);
        wt_row_core(coef, sb, sp, i0 + (t >> 2), o0 + (t & 3),
                    Wt + (size_t)l * O_DIM * KDIM);
    } else {
        int e = (b - WT_BLOCKS) * 256 + t;
        features_core(x0[e], gr0, F0 + (size_t)e * KPI);
    }
}

// ---------------------------------------------------------------------------
// GEMM (R10-verified counted-vmcnt depth-2 K-loop, byte-identical) + fused
// fence-free splitK reduction + fused feature build / final output.
//
// Epilogue protocol (fence-free; fixes R7's +50us/dispatch threadfence storm):
//   1. store P partials with agent-scope sc1 stores -> land at L3 directly,
//      no dirty L2 lines anywhere.
//   2. explicit vmcnt(0) + __syncthreads -> all this block's stores complete.
//   3. tid0: plain device-scope atomicAdd on ticket (RMW at coherence point).
//   4. 4th arriver re-reads the 4 partials with agent-scope sc1 loads
//      (bypass L1/L2 -> L3) -- correct regardless of XCD placement (G16-ok).
//   5. winner sums in s-order 0..3 (bit-identical to old reduce kernels) and
//      builds next-layer features into Fn (triple-buffered F -> no race) or
//      writes out. No spinning anywhere -> deadlock-free.
// ---------------------------------------------------------------------------
__global__ __launch_bounds__(256)
void gemm_fused(const __hip_bfloat16* __restrict__ A,   // [NBATCH][KDIM]
                const __hip_bfloat16* __restrict__ Wt,  // [O_DIM][KDIM]
                float* __restrict__ P,                  // [SPLITK][NBATCH][O_DIM]
                const float* __restrict__ grid_next,    // next-layer knot row
                __hip_bfloat16* __restrict__ Fn,        // next-layer features
                float* __restrict__ out,                // final output
                int last,
                int* __restrict__ ctr) {                // [128] tickets
    __shared__ __hip_bfloat16 lA[2][BM * BK];   // 2 x 16 KB
    __shared__ __hip_bfloat16 lB[2][BN * BK];   // 2 x 16 KB
    __shared__ int win;

    int bm = blockIdx.x;        // 0..15
    int bn = blockIdx.y;        // 0..7
    int ks = blockIdx.z;        // 0..3
    int tid = threadIdx.x;
    int lane = tid & 63;
    int wave = tid >> 6;        // 0..3
    int wr = (wave & 1) * 32;
    int wc = (wave >> 1) * 32;
    int q  = lane >> 4;         // 0..3
    int ln = lane & 15;

    f32x4 acc[2][2];
#pragma unroll
    for (int a = 0; a < 2; ++a)
#pragma unroll
        for (int b = 0; b < 2; ++b) acc[a][b] = (f32x4){0.f, 0.f, 0.f, 0.f};

    const __hip_bfloat16* Abase = A  + (size_t)(bm * BM) * KDIM + ks * KSEG;
    const __hip_bfloat16* Bbase = Wt + (size_t)(bn * BN) * KDIM + ks * KSEG;

    size_t goff[4];
    int    loff[4];
#pragma unroll
    for (int c = 0; c < 4; ++c) {
        int cc = wave * 256 + c * 64 + lane;
        int r = cc >> 4, j = (cc & 15) ^ (r & 7);
        goff[c] = (size_t)r * KDIM + j * 8;
        loff[c] = (wave * 256 + c * 64) * 8;
    }

#define STAGE(buf, kt)                                                        \
    do {                                                                      \
        _Pragma("unroll")                                                     \
        for (int c = 0; c < 4; ++c)                                           \
            gload_lds16(Abase + goff[c] + (kt), &lA[buf][loff[c]]);           \
        _Pragma("unroll")                                                     \
        for (int c = 0; c < 4; ++c)                                           \
            gload_lds16(Bbase + goff[c] + (kt), &lB[buf][loff[c]]);           \
    } while (0)

#define COMPUTE(buf)                                                          \
    do {                                                                      \
        _Pragma("unroll")                                                     \
        for (int kh = 0; kh < 4; ++kh) {                                      \
            bf16x8 af[2], bfr[2];                                             \
            _Pragma("unroll")                                                 \
            for (int rt = 0; rt < 2; ++rt) {                                  \
                int row = wr + rt * 16 + ln;                                  \
                af[rt] = *(const bf16x8*)(&lA[buf][0] + row * BK +            \
                                          (((kh * 4 + q) ^ (row & 7)) * 8));  \
            }                                                                 \
            _Pragma("unroll")                                                 \
            for (int ct = 0; ct < 2; ++ct) {                                  \
                int row = wc + ct * 16 + ln;                                  \
                bfr[ct] = *(const bf16x8*)(&lB[buf][0] + row * BK +           \
                                           (((kh * 4 + q) ^ (row & 7)) * 8)); \
            }                                                                 \
            _Pragma("unroll")                                                 \
            for (int rt = 0; rt < 2; ++rt)                                    \
                _Pragma("unroll")                                             \
                for (int ct = 0; ct < 2; ++ct)                                \
                    acc[rt][ct] = __builtin_amdgcn_mfma_f32_16x16x32_bf16(    \
                        af[rt], bfr[ct], acc[rt][ct], 0, 0, 0);               \
        }                                                                     \
    } while (0)

    STAGE(0, 0);
    STAGE(1, BK);                         // 16 loads in flight

    for (int t = 0; t < NT; t += 2) {
        asm volatile("s_waitcnt vmcnt(8)" ::: "memory");   // tile t landed
        __builtin_amdgcn_s_barrier();
        __builtin_amdgcn_sched_barrier(0);
        COMPUTE(0);
        __builtin_amdgcn_s_barrier();                      // buf0 consumed
        __builtin_amdgcn_sched_barrier(0);
        if (t + 2 < NT) STAGE(0, (t + 2) * BK);
        if (t + 3 < NT) {
            asm volatile("s_waitcnt vmcnt(8)" ::: "memory");
        } else {
            asm volatile("s_waitcnt vmcnt(0)" ::: "memory");
        }
        __builtin_amdgcn_s_barrier();
        __builtin_amdgcn_sched_barrier(0);
        COMPUTE(1);
        __builtin_amdgcn_s_barrier();
        __builtin_amdgcn_sched_barrier(0);
        if (t + 3 < NT) STAGE(1, (t + 3) * BK);
    }
#undef STAGE
#undef COMPUTE

    // ---- epilogue: sc1 partial stores (C/D layout col=lane&15, row=q*4+r) ----
    float* Pp = P + (size_t)ks * NBATCH * O_DIM;
    int orow = bm * BM + wr;
    int ocol = bn * BN + wc + ln;
#pragma unroll
    for (int rt = 0; rt < 2; ++rt)
#pragma unroll
        for (int ct = 0; ct < 2; ++ct)
#pragma unroll
            for (int r = 0; r < 4; ++r)
                st_dev(&Pp[(size_t)(orow + rt * 16 + q * 4 + r) * O_DIM + ocol + ct * 16],
                       acc[rt][ct][r]);

    // ---- fence-free splitK ticket ----
    asm volatile("s_waitcnt vmcnt(0)" ::: "memory");   // partials at L3
    __syncthreads();
    if (tid == 0) win = (atomicAdd(&ctr[bm * 8 + bn], 1) == SPLITK - 1);
    __syncthreads();
    if (win) {
        // 64x64 patch: 4096 (b,o) pairs, 16/thread; consecutive tid ->
        // consecutive o -> coalesced sc1 loads from L3.
#pragma unroll
        for (int it = 0; it < 16; ++it) {
            int p = it * 256 + tid;
            int b = bm * BM + (p >> 6);
            int o = bn * BN + (p & 63);
            float xv = 0.f;
#pragma unroll
            for (int s = 0; s < SPLITK; ++s)
                xv += ld_dev(&P[(size_t)s * NBATCH * O_DIM + (size_t)b * O_DIM + o]);
            if (!last)
                features_core(xv, grid_next, Fn + (size_t)b * KDIM + o * KPI);
            else
                out[(size_t)b * O_DIM + o] = xv;
        }
    }
}

// ---------------------------------------------------------------------------
extern "C" void kernel_launch(void* const* d_in, const int* in_sizes, int n_in,
                              void* d_out, int out_size, void* d_ws, size_t ws_size,
                              hipStream_t stream) {
    const float* x0  = (const float*)d_in[0];
    const float* gr0 = (const float*)d_in[1];
    const float* c0  = (const float*)d_in[2];
    const float* sb0 = (const float*)d_in[3];
    const float* sp0 = (const float*)d_in[4];
    const float* gr1 = (const float*)d_in[5];
    const float* c1  = (const float*)d_in[6];
    const float* sb1 = (const float*)d_in[7];
    const float* sp1 = (const float*)d_in[8];
    const float* gr2 = (const float*)d_in[9];
    const float* c2  = (const float*)d_in[10];
    const float* sb2 = (const float*)d_in[11];
    const float* sp2 = (const float*)d_in[12];

    char* ws = (char*)d_ws;
    const size_t wt_bytes = (size_t)O_DIM * KDIM * sizeof(__hip_bfloat16);   // 6.3 MB/layer
    const size_t f_bytes  = (size_t)NBATCH * KDIM * sizeof(__hip_bfloat16);  // 12.6 MB
    __hip_bfloat16* Wt = (__hip_bfloat16*)ws;                    // 3 layers contiguous
    __hip_bfloat16* F0 = (__hip_bfloat16*)(ws + 3 * wt_bytes);   // triple-buffered F
    __hip_bfloat16* F1 = F0 + (size_t)NBATCH * KDIM;
    __hip_bfloat16* F2 = F1 + (size_t)NBATCH * KDIM;
    float* P  = (float*)(ws + 3 * wt_bytes + 3 * f_bytes);       // [4][1024][512] = 8.4 MB
    int* ctr  = (int*)(P + (size_t)SPLITK * NBATCH * O_DIM);     // [3][128] tickets
    float* out = (float*)d_out;

    prep_kernel<<<WT_BLOCKS + FEAT_BLOCKS, 256, 0, stream>>>(
        x0, gr0, c0, sb0, sp0, c1, sb1, sp1, c2, sb2, sp2, Wt, F0, ctr);

    dim3 gg(NBATCH / BM, O_DIM / BN, SPLITK);
    gemm_fused<<<gg, 256, 0, stream>>>(F0, Wt, P, gr1, F1, out, 0, ctr);
    gemm_fused<<<gg, 256, 0, stream>>>(F1, Wt + (size_t)O_DIM * KDIM, P,
                                       gr2, F2, out, 0, ctr + 128);
    gemm_fused<<<gg, 256, 0, stream>>>(F2, Wt + (size_t)2 * O_DIM * KDIM, P,
                                       nullptr, nullptr, out, 1, ctr + 256);
}

// Round 13
// 176.452 us; speedup vs baseline: 1.1371x; 1.1371x over previous
//
#include <hip/hip_runtime.h>
#include <hip/hip_bf16.h>

#define I_DIM  512
#define O_DIM  512
#define NBATCH 1024
#define NSPL   8            // spline coeffs per input channel
#define KPI    12           // K slots per input channel: 8 spline + s_hi,s_hi,s_lo,0
#define KDIM   (I_DIM * KPI)   // 6144
#define NGRID  12           // extended grid points per channel

#define SPLITK 4
#define KSEG   (KDIM / SPLITK) // 1536
#define BK     128             // bf16 elems per LDS row; 256 B
#define BM     64
#define BN     64
#define NT     (KSEG / BK)     // 12 K-iterations (even)

typedef __attribute__((ext_vector_type(8))) short bf16x8;
typedef __attribute__((ext_vector_type(4))) float f32x4;

// ---------------------------------------------------------------------------
// async global->LDS 16B: dest = wave-uniform base + lane*16 (m97/m104 semantics)
// ---------------------------------------------------------------------------
__device__ __forceinline__ void gload_lds16(const __hip_bfloat16* g, __hip_bfloat16* l) {
    __builtin_amdgcn_global_load_lds(
        (const __attribute__((address_space(1))) void*)g,
        (__attribute__((address_space(3))) void*)l, 16, 0, 0);
}

// ---------------------------------------------------------------------------
// Feature row: F[b][i*12+slot] = [B0..B7, s_hi, s_hi, s_lo, 0] (bf16).
// R8: grid is broadcast linspace -> shared knot row, uniform spacing ->
// 3 reciprocals replace 54 divides (-21us measured).
// ---------------------------------------------------------------------------
__device__ __forceinline__ void features_core(float xv, const float* __restrict__ grid,
                                              __hip_bfloat16* __restrict__ dst) {
    float g[NGRID];
#pragma unroll
    for (int j = 0; j < NGRID; ++j) g[j] = grid[j];   // uniform across lanes

    float h  = g[1] - g[0];
    float r1 = 1.0f / h;
    float r2 = 1.0f / (2.0f * h);
    float r3 = 1.0f / (3.0f * h);

    float B[NGRID - 1];
#pragma unroll
    for (int j = 0; j < NGRID - 1; ++j)
        B[j] = (xv >= g[j] && xv < g[j + 1]) ? 1.0f : 0.0f;

#pragma unroll
    for (int j = 0; j < NGRID - 2; ++j)
        B[j] = (xv - g[j]) * r1 * B[j] + (g[j + 2] - xv) * r1 * B[j + 1];
#pragma unroll
    for (int j = 0; j < NGRID - 3; ++j)
        B[j] = (xv - g[j]) * r2 * B[j] + (g[j + 3] - xv) * r2 * B[j + 1];
#pragma unroll
    for (int j = 0; j < NGRID - 4; ++j)
        B[j] = (xv - g[j]) * r3 * B[j] + (g[j + 4] - xv) * r3 * B[j + 1];

    float s = xv / (1.0f + __expf(-xv));  // silu
    __hip_bfloat16 shi = __float2bfloat16(s);
    __hip_bfloat16 slo = __float2bfloat16(s - __bfloat162float(shi));

    __align__(16) __hip_bfloat16 row[KPI];
#pragma unroll
    for (int k = 0; k < NSPL; ++k) row[k] = __float2bfloat16(B[k]);
    row[8]  = shi;
    row[9]  = shi;
    row[10] = slo;
    row[11] = __float2bfloat16(0.0f);

    uint2* d = (uint2*)dst;
    const uint2* srow = (const uint2*)row;
    d[0] = srow[0]; d[1] = srow[1]; d[2] = srow[2];
}

__device__ __forceinline__ void wt_row_core(const float* __restrict__ coef,
                                            const float* __restrict__ sb,
                                            const float* __restrict__ sp,
                                            int i, int o,
                                            __hip_bfloat16* __restrict__ W) {
    float sbv = sb[i * O_DIM + o];
    float spv = sp[i * O_DIM + o];
    const float* cf = coef + (size_t)(i * O_DIM + o) * NSPL;
    __align__(16) __hip_bfloat16 row[KPI];
#pragma unroll
    for (int k = 0; k < NSPL; ++k) row[k] = __float2bfloat16(spv * cf[k]);
    __hip_bfloat16 whi = __float2bfloat16(sbv);
    __hip_bfloat16 wlo = __float2bfloat16(sbv - __bfloat162float(whi));
    row[8]  = whi;
    row[9]  = wlo;
    row[10] = whi;
    row[11] = __float2bfloat16(0.0f);
    uint2* dst = (uint2*)(W + (size_t)o * KDIM + i * KPI);
    const uint2* src = (const uint2*)row;
    dst[0] = src[0]; dst[1] = src[1]; dst[2] = src[2];
}

// ---------------------------------------------------------------------------
// prep: one launch for Wt-build (all 3 layers) + layer-0 features.
// ---------------------------------------------------------------------------
#define WT_BLOCKS   3072   // 3 layers x (8 i-tiles x 128 o-tiles)
#define FEAT_BLOCKS 2048   // NBATCH*I_DIM / 256
__global__ __launch_bounds__(256)
void prep_kernel(const float* __restrict__ x0, const float* __restrict__ gr0,
                 const float* __restrict__ c0, const float* __restrict__ sb0, const float* __restrict__ sp0,
                 const float* __restrict__ c1, const float* __restrict__ sb1, const float* __restrict__ sp1,
                 const float* __restrict__ c2, const float* __restrict__ sb2, const float* __restrict__ sp2,
                 __hip_bfloat16* __restrict__ Wt,   // [3][O_DIM][KDIM]
                 __hip_bfloat16* __restrict__ F) {  // [NBATCH][KDIM]
    int b = blockIdx.x;
    int t = threadIdx.x;
    if (b < WT_BLOCKS) {
        int l   = b >> 10;            // 0..2
        int rem = b & 1023;
        int i0  = (rem & 7) * 64;     // 8 i-tiles
        int o0  = (rem >> 3) * 4;     // 128 o-tiles
        const float* coef = l == 0 ? c0  : (l == 1 ? c1  : c2);
        const float* sb   = l == 0 ? sb0 : (l == 1 ? sb1 : sb2);
        const float* sp   = l == 0 ? sp0 : (l == 1 ? sp1 : sp2);
        wt_row_core(coef, sb, sp, i0 + (t >> 2), o0 + (t & 3),
                    Wt + (size_t)l * O_DIM * KDIM);
    } else {
        int e = (b - WT_BLOCKS) * 256 + t;
        features_core(x0[e], gr0, F + (size_t)e * KPI);
    }
}

// ---------------------------------------------------------------------------
// featsum (x4 per thread, float4 P loads) and reduce (x4 float4).
// ---------------------------------------------------------------------------
__global__ __launch_bounds__(256)
void build_features_sum(const float* __restrict__ P,  // [SPLITK][NBATCH*I_DIM]
                        const float* __restrict__ grid,
                        __hip_bfloat16* __restrict__ F) {
    int e0 = (blockIdx.x * blockDim.x + threadIdx.x) * 4;
    f32x4 xv = (f32x4){0.f, 0.f, 0.f, 0.f};
#pragma unroll
    for (int s = 0; s < SPLITK; ++s) {
        f32x4 v = *(const f32x4*)&P[(size_t)s * NBATCH * I_DIM + e0];
        xv.x += v.x; xv.y += v.y; xv.z += v.z; xv.w += v.w;
    }
    features_core(xv.x, grid, F + (size_t)(e0 + 0) * KPI);
    features_core(xv.y, grid, F + (size_t)(e0 + 1) * KPI);
    features_core(xv.z, grid, F + (size_t)(e0 + 2) * KPI);
    features_core(xv.w, grid, F + (size_t)(e0 + 3) * KPI);
}

__global__ __launch_bounds__(256)
void reduce_out(const float* __restrict__ P, float* __restrict__ out) {
    int e0 = (blockIdx.x * blockDim.x + threadIdx.x) * 4;
    f32x4 v0 = (f32x4){0.f, 0.f, 0.f, 0.f};
#pragma unroll
    for (int s = 0; s < SPLITK; ++s) {
        f32x4 v = *(const f32x4*)&P[(size_t)s * NBATCH * O_DIM + e0];
        v0.x += v.x; v0.y += v.y; v0.z += v.z; v0.w += v.w;
    }
    *(f32x4*)&out[e0] = v0;
}

// ---------------------------------------------------------------------------
// GEMM: P[ks][b,o] = sum_{k in seg ks} F[b,k] * Wt[o][k]   (bf16 MFMA, fp32 acc)
// R12 = R10-verified counted-vmcnt depth-2 pipeline (byte-identical K-loop)
// + XCD-EXCLUSIVE flat-grid partition (R6's mapping, retested now that the
// GEMM is latency-hidden and plausibly staging-BW-bound):
//   xcd = bid&7 (round-robin dispatch); each XCD owns (ks = xcd&3,
//   bm-half = xcd>>2): A slice 512 rows x KSEG + B slice 512 rows x KSEG
//   = 3 MB < 4 MiB L2. Every A/B byte crosses L3 once (24 MB vs 200 MB);
//   re-reads served from XCD-local L2. Zero extra instructions -> clean A/B
//   on the "is the pipelined GEMM BW-bound" question.
// ---------------------------------------------------------------------------
__global__ __launch_bounds__(256)
void gemm_kernel(const __hip_bfloat16* __restrict__ A,   // [NBATCH][KDIM]
                 const __hip_bfloat16* __restrict__ Wt,  // [O_DIM][KDIM]
                 float* __restrict__ P) {                // [SPLITK][NBATCH][O_DIM]
    __shared__ __hip_bfloat16 lA[2][BM * BK];   // 2 x 16 KB
    __shared__ __hip_bfloat16 lB[2][BN * BK];   // 2 x 16 KB

    int bid  = blockIdx.x;      // 0..511, flat
    int xcd  = bid & 7;         // == XCD id under round-robin dispatch
    int idx  = bid >> 3;        // 0..63 within this XCD
    int ks   = xcd & 3;         // XCD-exclusive K-segment
    int bm   = (xcd >> 2) * 8 + (idx >> 3);   // bm half per XCD, 0..15
    int bn   = idx & 7;         // 0..7
    int tid = threadIdx.x;
    int lane = tid & 63;
    int wave = tid >> 6;        // 0..3
    int wr = (wave & 1) * 32;
    int wc = (wave >> 1) * 32;
    int q  = lane >> 4;         // 0..3
    int ln = lane & 15;

    f32x4 acc[2][2];
#pragma unroll
    for (int a = 0; a < 2; ++a)
#pragma unroll
        for (int b = 0; b < 2; ++b) acc[a][b] = (f32x4){0.f, 0.f, 0.f, 0.f};

    const __hip_bfloat16* Abase = A  + (size_t)(bm * BM) * KDIM + ks * KSEG;
    const __hip_bfloat16* Bbase = Wt + (size_t)(bn * BN) * KDIM + ks * KSEG;

    // staging lane map (verified R9/R10): 1024 chunks (64 rows x 16), 4
    // calls/wave per operand; row r = cc>>4, source chunk j = (cc&15)^(r&7).
    size_t goff[4];
    int    loff[4];
#pragma unroll
    for (int c = 0; c < 4; ++c) {
        int cc = wave * 256 + c * 64 + lane;
        int r = cc >> 4, j = (cc & 15) ^ (r & 7);
        goff[c] = (size_t)r * KDIM + j * 8;
        loff[c] = (wave * 256 + c * 64) * 8;
    }

#define STAGE(buf, kt)                                                        \
    do {                                                                      \
        _Pragma("unroll")                                                     \
        for (int c = 0; c < 4; ++c)                                           \
            gload_lds16(Abase + goff[c] + (kt), &lA[buf][loff[c]]);           \
        _Pragma("unroll")                                                     \
        for (int c = 0; c < 4; ++c)                                           \
            gload_lds16(Bbase + goff[c] + (kt), &lB[buf][loff[c]]);           \
    } while (0)

#define COMPUTE(buf)                                                          \
    do {                                                                      \
        _Pragma("unroll")                                                     \
        for (int kh = 0; kh < 4; ++kh) {                                      \
            bf16x8 af[2], bfr[2];                                             \
            _Pragma("unroll")                                                 \
            for (int rt = 0; rt < 2; ++rt) {                                  \
                int row = wr + rt * 16 + ln;                                  \
                af[rt] = *(const bf16x8*)(&lA[buf][0] + row * BK +            \
                                          (((kh * 4 + q) ^ (row & 7)) * 8));  \
            }                                                                 \
            _Pragma("unroll")                                                 \
            for (int ct = 0; ct < 2; ++ct) {                                  \
                int row = wc + ct * 16 + ln;                                  \
                bfr[ct] = *(const bf16x8*)(&lB[buf][0] + row * BK +           \
                                           (((kh * 4 + q) ^ (row & 7)) * 8)); \
            }                                                                 \
            _Pragma("unroll")                                                 \
            for (int rt = 0; rt < 2; ++rt)                                    \
                _Pragma("unroll")                                             \
                for (int ct = 0; ct < 2; ++ct)                                \
                    acc[rt][ct] = __builtin_amdgcn_mfma_f32_16x16x32_bf16(    \
                        af[rt], bfr[ct], acc[rt][ct], 0, 0, 0);               \
        }                                                                     \
    } while (0)

    STAGE(0, 0);
    STAGE(1, BK);                         // 16 loads in flight

    for (int t = 0; t < NT; t += 2) {
        // ---- even tile t (buf0) ----
        asm volatile("s_waitcnt vmcnt(8)" ::: "memory");   // tile t landed
        __builtin_amdgcn_s_barrier();                      // all waves' loads in
        __builtin_amdgcn_sched_barrier(0);
        COMPUTE(0);
        __builtin_amdgcn_s_barrier();                      // buf0 fully consumed
        __builtin_amdgcn_sched_barrier(0);
        if (t + 2 < NT) STAGE(0, (t + 2) * BK);
        // ---- odd tile t+1 (buf1) ----
        if (t + 3 < NT) {
            asm volatile("s_waitcnt vmcnt(8)" ::: "memory");
        } else {
            asm volatile("s_waitcnt vmcnt(0)" ::: "memory");  // last tile: drain
        }
        __builtin_amdgcn_s_barrier();
        __builtin_amdgcn_sched_barrier(0);
        COMPUTE(1);
        __builtin_amdgcn_s_barrier();
        __builtin_amdgcn_sched_barrier(0);
        if (t + 3 < NT) STAGE(1, (t + 3) * BK);
    }
#undef STAGE
#undef COMPUTE

    // epilogue: C/D layout col = lane&15, row = quad*4 + reg (round-0 verified)
    float* Pp = P + (size_t)ks * NBATCH * O_DIM;
    int orow = bm * BM + wr;
    int ocol = bn * BN + wc + ln;
#pragma unroll
    for (int rt = 0; rt < 2; ++rt)
#pragma unroll
        for (int ct = 0; ct < 2; ++ct)
#pragma unroll
            for (int r = 0; r < 4; ++r)
                Pp[(size_t)(orow + rt * 16 + q * 4 + r) * O_DIM + ocol + ct * 16]
                    = acc[rt][ct][r];
}

// ---------------------------------------------------------------------------
extern "C" void kernel_launch(void* const* d_in, const int* in_sizes, int n_in,
                              void* d_out, int out_size, void* d_ws, size_t ws_size,
                              hipStream_t stream) {
    const float* x0  = (const float*)d_in[0];
    const float* gr0 = (const float*)d_in[1];
    const float* c0  = (const float*)d_in[2];
    const float* sb0 = (const float*)d_in[3];
    const float* sp0 = (const float*)d_in[4];
    const float* gr1 = (const float*)d_in[5];
    const float* c1  = (const float*)d_in[6];
    const float* sb1 = (const float*)d_in[7];
    const float* sp1 = (const float*)d_in[8];
    const float* gr2 = (const float*)d_in[9];
    const float* c2  = (const float*)d_in[10];
    const float* sb2 = (const float*)d_in[11];
    const float* sp2 = (const float*)d_in[12];

    char* ws = (char*)d_ws;
    const size_t wt_bytes = (size_t)O_DIM * KDIM * sizeof(__hip_bfloat16);   // 6.3 MB/layer
    const size_t f_bytes  = (size_t)NBATCH * KDIM * sizeof(__hip_bfloat16);  // 12.6 MB
    __hip_bfloat16* Wt = (__hip_bfloat16*)ws;                  // 3 layers contiguous
    __hip_bfloat16* F  = (__hip_bfloat16*)(ws + 3 * wt_bytes);
    float* P = (float*)(ws + 3 * wt_bytes + f_bytes);          // [4][1024][512] = 8.4 MB
    float* out = (float*)d_out;

    prep_kernel<<<WT_BLOCKS + FEAT_BLOCKS, 256, 0, stream>>>(
        x0, gr0, c0, sb0, sp0, c1, sb1, sp1, c2, sb2, sp2, Wt, F);

    gemm_kernel<<<512, 256, 0, stream>>>(F, Wt, P);

    build_features_sum<<<(NBATCH * I_DIM) / 1024, 256, 0, stream>>>(P, gr1, F);
    gemm_kernel<<<512, 256, 0, stream>>>(F, Wt + (size_t)O_DIM * KDIM, P);

    build_features_sum<<<(NBATCH * I_DIM) / 1024, 256, 0, stream>>>(P, gr2, F);
    gemm_kernel<<<512, 256, 0, stream>>>(F, Wt + (size_t)2 * O_DIM * KDIM, P);

    reduce_out<<<(NBATCH * O_DIM) / 1024, 256, 0, stream>>>(P, out);
}

// Round 14
// 170.176 us; speedup vs baseline: 1.1791x; 1.0369x over previous
//
#include <hip/hip_runtime.h>
#include <hip/hip_bf16.h>

#define I_DIM  512
#define O_DIM  512
#define NBATCH 1024
#define NSPL   8            // spline coeffs per input channel
#define KPI    12           // K slots per input channel: 8 spline + s_hi,s_hi,s_lo,0
#define KDIM   (I_DIM * KPI)   // 6144
#define NGRID  12           // extended grid points per channel

#define SPLITK 4
#define KSEG   (KDIM / SPLITK) // 1536
#define BK     128             // bf16 elems per LDS row; 256 B
#define BM     64
#define BN     64
#define NT     (KSEG / BK)     // 12 K-iterations (even)

typedef __attribute__((ext_vector_type(8))) short bf16x8;
typedef __attribute__((ext_vector_type(4))) float f32x4;

// ---------------------------------------------------------------------------
// async global->LDS 16B: dest = wave-uniform base + lane*16 (m97/m104 semantics)
// ---------------------------------------------------------------------------
__device__ __forceinline__ void gload_lds16(const __hip_bfloat16* g, __hip_bfloat16* l) {
    __builtin_amdgcn_global_load_lds(
        (const __attribute__((address_space(1))) void*)g,
        (__attribute__((address_space(3))) void*)l, 16, 0, 0);
}

// ---------------------------------------------------------------------------
// Feature row: F[b][i*12+slot] = [B0..B7, s_hi, s_hi, s_lo, 0] (bf16).
// R8: grid is broadcast linspace -> shared knot row, uniform spacing ->
// 3 reciprocals replace 54 divides (-21us measured).
// ---------------------------------------------------------------------------
__device__ __forceinline__ void features_core(float xv, const float* __restrict__ grid,
                                              __hip_bfloat16* __restrict__ dst) {
    float g[NGRID];
#pragma unroll
    for (int j = 0; j < NGRID; ++j) g[j] = grid[j];   // uniform across lanes

    float h  = g[1] - g[0];
    float r1 = 1.0f / h;
    float r2 = 1.0f / (2.0f * h);
    float r3 = 1.0f / (3.0f * h);

    float B[NGRID - 1];
#pragma unroll
    for (int j = 0; j < NGRID - 1; ++j)
        B[j] = (xv >= g[j] && xv < g[j + 1]) ? 1.0f : 0.0f;

#pragma unroll
    for (int j = 0; j < NGRID - 2; ++j)
        B[j] = (xv - g[j]) * r1 * B[j] + (g[j + 2] - xv) * r1 * B[j + 1];
#pragma unroll
    for (int j = 0; j < NGRID - 3; ++j)
        B[j] = (xv - g[j]) * r2 * B[j] + (g[j + 3] - xv) * r2 * B[j + 1];
#pragma unroll
    for (int j = 0; j < NGRID - 4; ++j)
        B[j] = (xv - g[j]) * r3 * B[j] + (g[j + 4] - xv) * r3 * B[j + 1];

    float s = xv / (1.0f + __expf(-xv));  // silu
    __hip_bfloat16 shi = __float2bfloat16(s);
    __hip_bfloat16 slo = __float2bfloat16(s - __bfloat162float(shi));

    __align__(16) __hip_bfloat16 row[KPI];
#pragma unroll
    for (int k = 0; k < NSPL; ++k) row[k] = __float2bfloat16(B[k]);
    row[8]  = shi;
    row[9]  = shi;
    row[10] = slo;
    row[11] = __float2bfloat16(0.0f);

    uint2* d = (uint2*)dst;
    const uint2* srow = (const uint2*)row;
    d[0] = srow[0]; d[1] = srow[1]; d[2] = srow[2];
}

__device__ __forceinline__ void wt_row_core(const float* __restrict__ coef,
                                            const float* __restrict__ sb,
                                            const float* __restrict__ sp,
                                            int i, int o,
                                            __hip_bfloat16* __restrict__ W) {
    float sbv = sb[i * O_DIM + o];
    float spv = sp[i * O_DIM + o];
    const float* cf = coef + (size_t)(i * O_DIM + o) * NSPL;
    __align__(16) __hip_bfloat16 row[KPI];
#pragma unroll
    for (int k = 0; k < NSPL; ++k) row[k] = __float2bfloat16(spv * cf[k]);
    __hip_bfloat16 whi = __float2bfloat16(sbv);
    __hip_bfloat16 wlo = __float2bfloat16(sbv - __bfloat162float(whi));
    row[8]  = whi;
    row[9]  = wlo;
    row[10] = whi;
    row[11] = __float2bfloat16(0.0f);
    uint2* dst = (uint2*)(W + (size_t)o * KDIM + i * KPI);
    const uint2* src = (const uint2*)row;
    dst[0] = src[0]; dst[1] = src[1]; dst[2] = src[2];
}

// ---------------------------------------------------------------------------
// prep: one launch for Wt-build (all 3 layers) + layer-0 features.
// ---------------------------------------------------------------------------
#define WT_BLOCKS   3072   // 3 layers x (8 i-tiles x 128 o-tiles)
#define FEAT_BLOCKS 2048   // NBATCH*I_DIM / 256
__global__ __launch_bounds__(256)
void prep_kernel(const float* __restrict__ x0, const float* __restrict__ gr0,
                 const float* __restrict__ c0, const float* __restrict__ sb0, const float* __restrict__ sp0,
                 const float* __restrict__ c1, const float* __restrict__ sb1, const float* __restrict__ sp1,
                 const float* __restrict__ c2, const float* __restrict__ sb2, const float* __restrict__ sp2,
                 __hip_bfloat16* __restrict__ Wt,   // [3][O_DIM][KDIM]
                 __hip_bfloat16* __restrict__ F) {  // [NBATCH][KDIM]
    int b = blockIdx.x;
    int t = threadIdx.x;
    if (b < WT_BLOCKS) {
        int l   = b >> 10;            // 0..2
        int rem = b & 1023;
        int i0  = (rem & 7) * 64;     // 8 i-tiles
        int o0  = (rem >> 3) * 4;     // 128 o-tiles
        const float* coef = l == 0 ? c0  : (l == 1 ? c1  : c2);
        const float* sb   = l == 0 ? sb0 : (l == 1 ? sb1 : sb2);
        const float* sp   = l == 0 ? sp0 : (l == 1 ? sp1 : sp2);
        wt_row_core(coef, sb, sp, i0 + (t >> 2), o0 + (t & 3),
                    Wt + (size_t)l * O_DIM * KDIM);
    } else {
        int e = (b - WT_BLOCKS) * 256 + t;
        features_core(x0[e], gr0, F + (size_t)e * KPI);
    }
}

// ---------------------------------------------------------------------------
// featsum (x4 per thread, float4 P loads) and reduce (x4 float4).
// ---------------------------------------------------------------------------
__global__ __launch_bounds__(256)
void build_features_sum(const float* __restrict__ P,  // [SPLITK][NBATCH*I_DIM]
                        const float* __restrict__ grid,
                        __hip_bfloat16* __restrict__ F) {
    int e0 = (blockIdx.x * blockDim.x + threadIdx.x) * 4;
    f32x4 xv = (f32x4){0.f, 0.f, 0.f, 0.f};
#pragma unroll
    for (int s = 0; s < SPLITK; ++s) {
        f32x4 v = *(const f32x4*)&P[(size_t)s * NBATCH * I_DIM + e0];
        xv.x += v.x; xv.y += v.y; xv.z += v.z; xv.w += v.w;
    }
    features_core(xv.x, grid, F + (size_t)(e0 + 0) * KPI);
    features_core(xv.y, grid, F + (size_t)(e0 + 1) * KPI);
    features_core(xv.z, grid, F + (size_t)(e0 + 2) * KPI);
    features_core(xv.w, grid, F + (size_t)(e0 + 3) * KPI);
}

__global__ __launch_bounds__(256)
void reduce_out(const float* __restrict__ P, float* __restrict__ out) {
    int e0 = (blockIdx.x * blockDim.x + threadIdx.x) * 4;
    f32x4 v0 = (f32x4){0.f, 0.f, 0.f, 0.f};
#pragma unroll
    for (int s = 0; s < SPLITK; ++s) {
        f32x4 v = *(const f32x4*)&P[(size_t)s * NBATCH * O_DIM + e0];
        v0.x += v.x; v0.y += v.y; v0.z += v.z; v0.w += v.w;
    }
    *(f32x4*)&out[e0] = v0;
}

// ---------------------------------------------------------------------------
// GEMM: P[ks][b,o] = sum_{k in seg ks} F[b,k] * Wt[o][k]   (bf16 MFMA, fp32 acc)
// R14 = R10 verbatim (best measured, 169.5us): counted-vmcnt depth-2
// pipeline (T4): wait vmcnt(8) [tile t landed, next tile's 8 loads stay in
// flight across the barrier], raw s_barrier, sched_barrier(0) (rule #18),
// ds_read+MFMA, raw s_barrier, stage t+2. splitK=4, BM=BN=64, 4 waves 2x2,
// wave tile 32x32 (acc[2][2]), XOR-swizzled LDS, global_load_lds w16,
// LDS 64KB -> 2 blocks/CU. R13's XCD remap reverted (measured -7us).
// GEMM runs ~800 TF effective = ~90% of the plain-HIP m97-structure ceiling.
// ---------------------------------------------------------------------------
__global__ __launch_bounds__(256)
void gemm_kernel(const __hip_bfloat16* __restrict__ A,   // [NBATCH][KDIM]
                 const __hip_bfloat16* __restrict__ Wt,  // [O_DIM][KDIM]
                 float* __restrict__ P) {                // [SPLITK][NBATCH][O_DIM]
    __shared__ __hip_bfloat16 lA[2][BM * BK];   // 2 x 16 KB
    __shared__ __hip_bfloat16 lB[2][BN * BK];   // 2 x 16 KB

    int bm = blockIdx.x;        // 0..15
    int bn = blockIdx.y;        // 0..7
    int ks = blockIdx.z;        // 0..3
    int tid = threadIdx.x;
    int lane = tid & 63;
    int wave = tid >> 6;        // 0..3
    int wr = (wave & 1) * 32;
    int wc = (wave >> 1) * 32;
    int q  = lane >> 4;         // 0..3
    int ln = lane & 15;

    f32x4 acc[2][2];
#pragma unroll
    for (int a = 0; a < 2; ++a)
#pragma unroll
        for (int b = 0; b < 2; ++b) acc[a][b] = (f32x4){0.f, 0.f, 0.f, 0.f};

    const __hip_bfloat16* Abase = A  + (size_t)(bm * BM) * KDIM + ks * KSEG;
    const __hip_bfloat16* Bbase = Wt + (size_t)(bn * BN) * KDIM + ks * KSEG;

    // staging lane map (verified R9/R10): 1024 chunks (64 rows x 16), 4
    // calls/wave per operand; row r = cc>>4, source chunk j = (cc&15)^(r&7).
    size_t goff[4];
    int    loff[4];
#pragma unroll
    for (int c = 0; c < 4; ++c) {
        int cc = wave * 256 + c * 64 + lane;
        int r = cc >> 4, j = (cc & 15) ^ (r & 7);
        goff[c] = (size_t)r * KDIM + j * 8;
        loff[c] = (wave * 256 + c * 64) * 8;
    }

#define STAGE(buf, kt)                                                        \
    do {                                                                      \
        _Pragma("unroll")                                                     \
        for (int c = 0; c < 4; ++c)                                           \
            gload_lds16(Abase + goff[c] + (kt), &lA[buf][loff[c]]);           \
        _Pragma("unroll")                                                     \
        for (int c = 0; c < 4; ++c)                                           \
            gload_lds16(Bbase + goff[c] + (kt), &lB[buf][loff[c]]);           \
    } while (0)

#define COMPUTE(buf)                                                          \
    do {                                                                      \
        _Pragma("unroll")                                                     \
        for (int kh = 0; kh < 4; ++kh) {                                      \
            bf16x8 af[2], bfr[2];                                             \
            _Pragma("unroll")                                                 \
            for (int rt = 0; rt < 2; ++rt) {                                  \
                int row = wr + rt * 16 + ln;                                  \
                af[rt] = *(const bf16x8*)(&lA[buf][0] + row * BK +            \
                                          (((kh * 4 + q) ^ (row & 7)) * 8));  \
            }                                                                 \
            _Pragma("unroll")                                                 \
            for (int ct = 0; ct < 2; ++ct) {                                  \
                int row = wc + ct * 16 + ln;                                  \
                bfr[ct] = *(const bf16x8*)(&lB[buf][0] + row * BK +           \
                                           (((kh * 4 + q) ^ (row & 7)) * 8)); \
            }                                                                 \
            _Pragma("unroll")                                                 \
            for (int rt = 0; rt < 2; ++rt)                                    \
                _Pragma("unroll")                                             \
                for (int ct = 0; ct < 2; ++ct)                                \
                    acc[rt][ct] = __builtin_amdgcn_mfma_f32_16x16x32_bf16(    \
                        af[rt], bfr[ct], acc[rt][ct], 0, 0, 0);               \
        }                                                                     \
    } while (0)

    STAGE(0, 0);
    STAGE(1, BK);                         // 16 loads in flight

    for (int t = 0; t < NT; t += 2) {
        // ---- even tile t (buf0); t+1 always < NT -> counted wait ----
        asm volatile("s_waitcnt vmcnt(8)" ::: "memory");   // tile t landed
        __builtin_amdgcn_s_barrier();                      // all waves' loads in
        __builtin_amdgcn_sched_barrier(0);
        COMPUTE(0);
        __builtin_amdgcn_s_barrier();                      // buf0 fully consumed
        __builtin_amdgcn_sched_barrier(0);
        if (t + 2 < NT) STAGE(0, (t + 2) * BK);
        // ---- odd tile t+1 (buf1) ----
        if (t + 3 < NT) {
            asm volatile("s_waitcnt vmcnt(8)" ::: "memory");
        } else {
            asm volatile("s_waitcnt vmcnt(0)" ::: "memory");  // last tile: drain
        }
        __builtin_amdgcn_s_barrier();
        __builtin_amdgcn_sched_barrier(0);
        COMPUTE(1);
        __builtin_amdgcn_s_barrier();
        __builtin_amdgcn_sched_barrier(0);
        if (t + 3 < NT) STAGE(1, (t + 3) * BK);
    }
#undef STAGE
#undef COMPUTE

    // epilogue: C/D layout col = lane&15, row = quad*4 + reg (round-0 verified)
    float* Pp = P + (size_t)ks * NBATCH * O_DIM;
    int orow = bm * BM + wr;
    int ocol = bn * BN + wc + ln;
#pragma unroll
    for (int rt = 0; rt < 2; ++rt)
#pragma unroll
        for (int ct = 0; ct < 2; ++ct)
#pragma unroll
            for (int r = 0; r < 4; ++r)
                Pp[(size_t)(orow + rt * 16 + q * 4 + r) * O_DIM + ocol + ct * 16]
                    = acc[rt][ct][r];
}

// ---------------------------------------------------------------------------
extern "C" void kernel_launch(void* const* d_in, const int* in_sizes, int n_in,
                              void* d_out, int out_size, void* d_ws, size_t ws_size,
                              hipStream_t stream) {
    const float* x0  = (const float*)d_in[0];
    const float* gr0 = (const float*)d_in[1];
    const float* c0  = (const float*)d_in[2];
    const float* sb0 = (const float*)d_in[3];
    const float* sp0 = (const float*)d_in[4];
    const float* gr1 = (const float*)d_in[5];
    const float* c1  = (const float*)d_in[6];
    const float* sb1 = (const float*)d_in[7];
    const float* sp1 = (const float*)d_in[8];
    const float* gr2 = (const float*)d_in[9];
    const float* c2  = (const float*)d_in[10];
    const float* sb2 = (const float*)d_in[11];
    const float* sp2 = (const float*)d_in[12];

    char* ws = (char*)d_ws;
    const size_t wt_bytes = (size_t)O_DIM * KDIM * sizeof(__hip_bfloat16);   // 6.3 MB/layer
    const size_t f_bytes  = (size_t)NBATCH * KDIM * sizeof(__hip_bfloat16);  // 12.6 MB
    __hip_bfloat16* Wt = (__hip_bfloat16*)ws;                  // 3 layers contiguous
    __hip_bfloat16* F  = (__hip_bfloat16*)(ws + 3 * wt_bytes);
    float* P = (float*)(ws + 3 * wt_bytes + f_bytes);          // [4][1024][512] = 8.4 MB
    float* out = (float*)d_out;

    prep_kernel<<<WT_BLOCKS + FEAT_BLOCKS, 256, 0, stream>>>(
        x0, gr0, c0, sb0, sp0, c1, sb1, sp1, c2, sb2, sp2, Wt, F);

    gemm_kernel<<<dim3(NBATCH / BM, O_DIM / BN, SPLITK), 256, 0, stream>>>(F, Wt, P);

    build_features_sum<<<(NBATCH * I_DIM) / 1024, 256, 0, stream>>>(P, gr1, F);
    gemm_kernel<<<dim3(NBATCH / BM, O_DIM / BN, SPLITK), 256, 0, stream>>>(
        F, Wt + (size_t)O_DIM * KDIM, P);

    build_features_sum<<<(NBATCH * I_DIM) / 1024, 256, 0, stream>>>(P, gr2, F);
    gemm_kernel<<<dim3(NBATCH / BM, O_DIM / BN, SPLITK), 256, 0, stream>>>(
        F, Wt + (size_t)2 * O_DIM * KDIM, P);

    reduce_out<<<(NBATCH * O_DIM) / 1024, 256, 0, stream>>>(P, out);
}